// Round 3
// baseline (617.752 us; speedup 1.0000x reference)
//
#include <hip/hip_runtime.h>

// Chunked VMM with per-128-K-chunk ADC quantization.
//   out[b,n] = sum_{c} q( sum_{k in chunk c} x[b,k]*w[n,k] ) + bias[n]
//   q(p) = round(clip(p,+-2.56) * 255/2.56) * 2.56/255   (round = RTNE)
// w pre-scaled by s=255/2.56 so GEMM partials are in ADC units.
//
// R6: phase-scheduled K-loop (T3+T4+T5 port of the 256^2 8-phase template).
//  Per BK=64 tile, 2 phases (K-halves kk=0/32). Each phase:
//    {8x ds_read_b128 -> 3x global_load_lds (w16) -> s_barrier ->
//     setprio(1) 16x mfma_16x16x32_bf16 setprio(0) -> s_barrier}
//  vmcnt(6) rides the tile's LAST barrier (after MFMA h1) so the next
//  tile's DMA drain overlaps compute; never drained to 0 mid-loop.
//  Quantize (fmed3+rndne+macc) moved into phase A of even tiles BEFORE the
//  first barrier: hides under ds_read drain + DMA instead of a solo bubble
//  (R5: 1024 cyc/CU serialized burst per 2 tiles = ~41% of MFMA time).
//  Carried from R5: XCD supertile map (8 m-tiles/XCD -> L2-resident staging),
//  row-major LDS tiles w/ chunk swizzle pc = lc^(row&7) (measured 0
//  conflicts), triple buffer 144 KiB, tile 128x256, 8 waves of 64x64.

typedef __attribute__((ext_vector_type(8))) short short8;            // 8 bf16
typedef __attribute__((ext_vector_type(8))) unsigned short ushort8;  // 16 B store
typedef __attribute__((ext_vector_type(4))) float floatx4;           // MFMA C/D

#define BM 128
#define BN 256
#define BK 64

#define AS1 __attribute__((address_space(1)))
#define AS3 __attribute__((address_space(3)))

static __device__ __forceinline__ unsigned short f2bf(float f) {
    union { float f; unsigned int u; } v; v.f = f;
    unsigned int u = v.u;
    unsigned int r = (u + 0x7fffu + ((u >> 16) & 1u)) >> 16;  // RTNE
    return (unsigned short)r;
}

// fp32 -> bf16 with scale; 8 elements/lane/iter: 32B read, 16B write.
__global__ void cast_kernel(const float* __restrict__ in,
                            unsigned short* __restrict__ out,
                            long n8, float s) {
    long i = (long)blockIdx.x * 256 + threadIdx.x;
    const long stride = (long)gridDim.x * 256;
    for (; i < n8; i += stride) {
        float4 a = ((const float4*)in)[2 * i];
        float4 b = ((const float4*)in)[2 * i + 1];
        ushort8 o;
        o[0] = f2bf(a.x * s); o[1] = f2bf(a.y * s);
        o[2] = f2bf(a.z * s); o[3] = f2bf(a.w * s);
        o[4] = f2bf(b.x * s); o[5] = f2bf(b.y * s);
        o[6] = f2bf(b.z * s); o[7] = f2bf(b.w * s);
        ((ushort8*)out)[i] = o;
    }
}

__global__ __launch_bounds__(512, 2) void vmm_kernel(
    const unsigned short* __restrict__ A,   // x   [B,K] bf16
    const unsigned short* __restrict__ Bw,  // w*s [N,K] bf16 (K-contiguous: B^T gemm)
    const float* __restrict__ bias,
    float* __restrict__ out,
    int N, int K)
{
    // Triple-buffered row-major tiles (shorts): sA[3][128][64], sB[3][256][64]
    __shared__ unsigned short sA[3 * BM * BK];   // 48 KiB
    __shared__ unsigned short sB[3 * BN * BK];   // 96 KiB

    const int tid  = threadIdx.x;
    const int wid  = tid >> 6;
    const int lane = tid & 63;

    // ---- XCD supertile block mapping (grid is 1-D, 1024 blocks) -----------
    const int ntn = N / BN;                      // 16
    int mt, ntile;
    if (gridDim.x == 1024 && ntn == 16) {
        const int g   = blockIdx.x & 7;
        const int idx = blockIdx.x >> 3;         // 0..127
        mt    = (g << 3) + ((idx >> 2) & 7);     // 0..63
        ntile = ((idx >> 5) << 2) + (idx & 3);   // 0..15
    } else {                                     // generic fallback
        mt = blockIdx.x / ntn;
        ntile = blockIdx.x - mt * ntn;
    }
    const int m0 = mt * BM;
    const int n0 = ntile * BN;

    const int waveM = (wid >> 2) * 64;   // 0,64
    const int waveN = (wid & 3) * 64;    // 0,64,128,192

    // ---- staging: wave-load = one 1KiB segment = 8 rows x 64 cols.
    // lane -> (row = lane>>3, physical chunk = lane&7); fetch logical chunk
    // (lane&7) ^ (row&7) so that pc = lc ^ (row&7).
    const int r0  = (wid << 3) + (lane >> 3);
    const int csw = (((lane & 7) ^ (lane >> 3)) << 3);
    const unsigned short* gA = A  + (long)(m0 + r0) * K + csw;
    const unsigned short* gB = Bw + (long)(n0 + r0) * K + csw;

    // ---- ds_read mapping: frag row = waveX + t*16 + (lane&15); logical
    // chunk = (kk>>3) + (lane>>4); pc = lc ^ (row&7), row&7 == lane&7.
    const int c0 = (((lane >> 4) ^ (lane & 7)) << 3);
    int aoff[4], boff[4];
    #pragma unroll
    for (int t = 0; t < 4; ++t) {
        aoff[t] = (waveM + t * 16 + (lane & 15)) * BK + c0;
        boff[t] = (waveN + t * 16 + (lane & 15)) * BK + c0;
    }
    // kk=32 half: offset ^ 32 (flips chunk bit2: (4^u)^v == (u^v)^4)

    floatx4 acc[4][4];   // partial (ADC units), quantized+reset every 128 K
    floatx4 macc[4][4];  // master accumulator
    #pragma unroll
    for (int i = 0; i < 4; ++i)
        #pragma unroll
        for (int j = 0; j < 4; ++j) {
            acc[i][j]  = (floatx4){0.f, 0.f, 0.f, 0.f};
            macc[i][j] = (floatx4){0.f, 0.f, 0.f, 0.f};
        }

    // 6 loads/tile in fixed program order (vmcnt FIFO): A0,A1,B0 | B1,B2,B3
    #define STAGE_A(buf, ko_) do {                                             \
        __builtin_amdgcn_global_load_lds((const AS1 void*)(gA + (ko_)),        \
            (AS3 void*)(sA + (buf) * 8192 + wid * 512), 16, 0, 0);             \
        __builtin_amdgcn_global_load_lds((const AS1 void*)(gA + 64 * (long)K + (ko_)), \
            (AS3 void*)(sA + (buf) * 8192 + 4096 + wid * 512), 16, 0, 0);      \
        __builtin_amdgcn_global_load_lds((const AS1 void*)(gB + (ko_)),        \
            (AS3 void*)(sB + (buf) * 16384 + wid * 512), 16, 0, 0);            \
    } while (0)
    #define STAGE_B(buf, ko_) do {                                             \
        __builtin_amdgcn_global_load_lds((const AS1 void*)(gB + 64 * (long)K + (ko_)), \
            (AS3 void*)(sB + (buf) * 16384 + 4096 + wid * 512), 16, 0, 0);     \
        __builtin_amdgcn_global_load_lds((const AS1 void*)(gB + 128 * (long)K + (ko_)), \
            (AS3 void*)(sB + (buf) * 16384 + 8192 + wid * 512), 16, 0, 0);     \
        __builtin_amdgcn_global_load_lds((const AS1 void*)(gB + 192 * (long)K + (ko_)), \
            (AS3 void*)(sB + (buf) * 16384 + 12288 + wid * 512), 16, 0, 0);    \
    } while (0)

    const int NT = K / BK;   // 64 tiles
    STAGE_A(0, 0); STAGE_B(0, 0);
    STAGE_A(1, BK); STAGE_B(1, BK);                      // 12 outstanding
    asm volatile("s_waitcnt vmcnt(6)\n\ts_barrier" ::: "memory");  // tile0 ready

    int buf = 0;
    for (int t = 0; t < NT; ++t) {
        const int nb = (buf >= 1) ? buf - 1 : 2;         // (t+2)%3
        const long ksrc = (long)(t + 2) * BK;
        const bool pf = (t + 2 < NT);
        const unsigned short* pa = sA + buf * 8192;
        const unsigned short* pb = sB + buf * 16384;

        // ================= phase A (kk = 0..31) =================
        short8 a0[4], b0[4];
        #pragma unroll
        for (int i = 0; i < 4; ++i) a0[i] = *(const short8*)(pa + aoff[i]);
        #pragma unroll
        for (int i = 0; i < 4; ++i) b0[i] = *(const short8*)(pb + boff[i]);
        if (pf) STAGE_A(nb, ksrc);

        // ADC quantize of the chunk completed at tile t-1 (even t only):
        // overlaps ds_read drain + DMA instead of a solo VALU bubble.
        if (t && !(t & 1)) {
            #pragma unroll
            for (int tm = 0; tm < 4; ++tm)
                #pragma unroll
                for (int tn = 0; tn < 4; ++tn) {
                    #pragma unroll
                    for (int r = 0; r < 4; ++r) {
                        float v = __builtin_rintf(
                            __builtin_amdgcn_fmed3f(acc[tm][tn][r], -255.0f, 255.0f));
                        macc[tm][tn][r] += v;
                    }
                    acc[tm][tn] = (floatx4){0.f, 0.f, 0.f, 0.f};
                }
        }

        asm volatile("s_barrier" ::: "memory");                    // B1
        __builtin_amdgcn_s_setprio(1);
        #pragma unroll
        for (int tm = 0; tm < 4; ++tm)
            #pragma unroll
            for (int tn = 0; tn < 4; ++tn)
                acc[tm][tn] = __builtin_amdgcn_mfma_f32_16x16x32_bf16(
                    a0[tm], b0[tn], acc[tm][tn], 0, 0, 0);
        __builtin_amdgcn_s_setprio(0);
        asm volatile("s_barrier" ::: "memory");                    // B2

        // ================= phase B (kk = 32..63) =================
        short8 a1[4], b1[4];
        #pragma unroll
        for (int i = 0; i < 4; ++i) a1[i] = *(const short8*)(pa + (aoff[i] ^ 32));
        #pragma unroll
        for (int i = 0; i < 4; ++i) b1[i] = *(const short8*)(pb + (boff[i] ^ 32));
        if (pf) STAGE_B(nb, ksrc);

        asm volatile("s_barrier" ::: "memory");                    // B3
        __builtin_amdgcn_s_setprio(1);
        #pragma unroll
        for (int tm = 0; tm < 4; ++tm)
            #pragma unroll
            for (int tn = 0; tn < 4; ++tn)
                acc[tm][tn] = __builtin_amdgcn_mfma_f32_16x16x32_bf16(
                    a1[tm], b1[tn], acc[tm][tn], 0, 0, 0);
        __builtin_amdgcn_s_setprio(0);
        // Tile t+1 readiness rides the closing barrier: drain to 6 (the 6
        // just-issued t+2 loads stay in flight). Peeled to 0 at the tail.
        if (pf) asm volatile("s_waitcnt vmcnt(6)\n\ts_barrier" ::: "memory");  // B4
        else    asm volatile("s_waitcnt vmcnt(0)\n\ts_barrier" ::: "memory");

        buf = (buf == 2) ? 0 : buf + 1;
    }

    // final chunk quantize (tile NT-1's acc)
    #pragma unroll
    for (int tm = 0; tm < 4; ++tm)
        #pragma unroll
        for (int tn = 0; tn < 4; ++tn)
            #pragma unroll
            for (int r = 0; r < 4; ++r) {
                float v = __builtin_rintf(
                    __builtin_amdgcn_fmed3f(acc[tm][tn][r], -255.0f, 255.0f));
                macc[tm][tn][r] += v;
            }

    const float invs = 2.56f / 255.0f;
    #pragma unroll
    for (int tn = 0; tn < 4; ++tn) {
        const int col = n0 + waveN + tn * 16 + (lane & 15);
        const float bv = bias[col];
        #pragma unroll
        for (int tm = 0; tm < 4; ++tm) {
            const int row = m0 + waveM + tm * 16 + (lane >> 4) * 4;
            #pragma unroll
            for (int r = 0; r < 4; ++r)
                out[(long)(row + r) * N + col] = macc[tm][tn][r] * invs + bv;
        }
    }
    #undef STAGE_A
    #undef STAGE_B
}

extern "C" void kernel_launch(void* const* d_in, const int* in_sizes, int n_in,
                              void* d_out, int out_size, void* d_ws, size_t ws_size,
                              hipStream_t stream) {
    const float* x    = (const float*)d_in[0];
    const float* w    = (const float*)d_in[1];
    const float* bias = (const float*)d_in[2];
    // d_in[3] = layer (unused)

    const int N = in_sizes[2];
    const int K = in_sizes[1] / N;
    const int B = in_sizes[0] / K;
    float* out = (float*)d_out;

    // workspace layout: bf16 x [B*K], bf16 w*s [N*K]  (needs ~101 MB)
    unsigned short* xb = (unsigned short*)d_ws;
    unsigned short* wb = xb + (size_t)B * K;

    cast_kernel<<<2048, 256, 0, stream>>>(x, xb, ((long)B * K) / 8, 1.0f);
    cast_kernel<<<2048, 256, 0, stream>>>(w, wb, ((long)N * K) / 8, 99.609375f);

    const int nblocks = (N / BN) * (B / BM);   // 16 * 64 = 1024
    vmm_kernel<<<nblocks, 512, 0, stream>>>(xb, wb, bias, out, N, K);
}